// Round 5
// baseline (102.514 us; speedup 1.0000x reference)
//
#include <hip/hip_runtime.h>
#include <math.h>

#define SDIM 376
#define ADIM 17
#define DIN  393
#define H1   400
#define H2   300
#define TSTEPS 32
#define KP 416   // 13*32 (padded DIN / padded H1 as K-dims)
#define NKT 13   // K tiles of 32
#define NT1 25   // n-tiles for H1 (400 cols, exact)
#define NT2 19   // n-tiles for H2 (304 padded cols)
#define LDA 424  // a_lds row stride in bf16 (pad 416+8: breaks 16-row bank aliasing)

typedef __bf16 bf16x8 __attribute__((ext_vector_type(8)));
typedef float  f32x4  __attribute__((ext_vector_type(4)));

// R4: amortize weight re-read. R3 post-mortem: ~10.5us of our code inside an ~82us
// harness-fill floor; mask_bound's dominant term = 256 blocks x 572KB unique weight
// stream = 146MB L2 traffic (4.3us) vs 1.2us MFMA floor.
//   - mask_bound: 64 rows/block (4 mtiles x 2 parities = 8 waves, 512 thr, grid 128)
//     -> unique weight traffic halves to 73MB. Same busy-SIMD count (512), same
//     2 waves/SIMD TLP, per-wave inner code identical to R3 (same thresholds/chain
//     order -> bitwise-identical decisions).
//   - prep_w: thread -> (8-k-run, n) remap: 8 coalesced reads + one 16B store
//     (was: one 2B store at 16B stride = 8x transaction amplification).

// ---------- K0: weights only. W1 -> B_sw | W2+ -> B2_sw ----------
__global__ __launch_bounds__(256) void prep_w(
    const float* __restrict__ W1, const float* __restrict__ W2,
    __bf16* __restrict__ B_sw, __bf16* __restrict__ B2_sw, int nw1) {
    const int bid = blockIdx.x, tid = threadIdx.x;
    if (bid < nw1) {
        // W1: thread handles k0..k0+7 (one e-run) for col n; per e, wave reads 256B
        // contiguous of W1; write is one contiguous bf16x8.
        int idx = bid * 256 + tid;
        if (idx >= 52 * H1) return;
        int kc = idx / H1, n = idx - kc * H1;
        int k0 = kc * 8;
        bf16x8 o;
        #pragma unroll
        for (int e = 0; e < 8; ++e) {
            int k = k0 + e;
            o[e] = (__bf16)((k < DIN) ? W1[(size_t)k * H1 + n] : 0.f);
        }
        int kt = k0 >> 5, qd = (k0 >> 3) & 3;
        *(bf16x8*)&B_sw[(((size_t)(n >> 4) * NKT + kt) * 64 + (qd << 4) + (n & 15)) * 8] = o;
    } else {
        // W2+ = max(W2,0): same mapping, n in [0,304) (pad cols write 0)
        int idx = (bid - nw1) * 256 + tid;
        if (idx >= 52 * 304) return;
        int kc = idx / 304, n = idx - kc * 304;
        int k0 = kc * 8;
        bf16x8 o;
        #pragma unroll
        for (int e = 0; e < 8; ++e) {
            int k = k0 + e;
            o[e] = (__bf16)((k < H1 && n < H2) ? fmaxf(W2[(size_t)k * H2 + n], 0.f) : 0.f);
        }
        int kt = k0 >> 5, qd = (k0 >> 3) & 3;
        *(bf16x8*)&B2_sw[(((size_t)(n >> 4) * NKT + kt) * 64 + (qd << 4) + (n & 15)) * 8] = o;
    }
}

// ---------- K1 (fused): pack -> layer-1 mask -> bound GEMM -> epilogue ----------
// 128 blocks x 512 thr (8 waves). Wave w: mtile m = w>>1 (16 rows), parity h = w&1
// (ntiles {h, h+2, ...}). Thresholds: mask 0.99 (superset of x1>=1), bound 0.92
// (bf16 undercount <= ~0.04; 0.92+0.04 < 0.999 => sound).
__global__ __launch_bounds__(512, 2) void mask_bound(
    const __bf16* __restrict__ B_sw, const __bf16* __restrict__ B2_sw,
    const float* __restrict__ state, const float* __restrict__ action,
    const float* __restrict__ W1, const float* __restrict__ b1,
    const float* __restrict__ W2, const float* __restrict__ b2,
    const float* __restrict__ W3, const float* __restrict__ b3,
    float* __restrict__ out) {
    const int tid = threadIdx.x;
    const int lane = tid & 63, w = tid >> 6;
    const int l16 = lane & 15, quad = lane >> 4;
    const int m = w >> 1, h = w & 1;
    const int base = blockIdx.x * 64;

    __shared__ __align__(16) __bf16 a_lds[64][LDA];            // 54272 B
    __shared__ __align__(16) unsigned short s_mask[64][32];    // 4096 B
    __shared__ unsigned s_ok[8];

    // zero mask chunks 25..31 (pad chunks must read as no-spike)
    if (tid < 448) { int rr = tid / 7, c7 = tid - rr * 7; s_mask[rr][25 + c7] = 0; }

    // ---- pack rows [base, base+64) -> a_lds (bf16 concat(state,action,0)) ----
    #pragma unroll
    for (int it = 0; it < 7; ++it) {
        int u = it * 512 + tid;
        if (u < 64 * 52) {
            int r = u / 52, cc = u - r * 52, g0 = cc * 8;
            const int grow = base + r;
            float v[8];
            if (g0 + 7 < SDIM) {
                float4 a = *(const float4*)&state[(size_t)grow * SDIM + g0];
                float4 b = *(const float4*)&state[(size_t)grow * SDIM + g0 + 4];
                v[0]=a.x; v[1]=a.y; v[2]=a.z; v[3]=a.w; v[4]=b.x; v[5]=b.y; v[6]=b.z; v[7]=b.w;
            } else {
                #pragma unroll
                for (int e = 0; e < 8; ++e) {
                    int k = g0 + e;
                    v[e] = (k < SDIM) ? state[(size_t)grow * SDIM + k]
                         : (k < DIN)  ? action[(size_t)grow * ADIM + k - SDIM] : 0.f;
                }
            }
            bf16x8 o;
            #pragma unroll
            for (int e = 0; e < 8; ++e) o[e] = (__bf16)v[e];
            *(bf16x8*)&a_lds[r][g0] = o;
        }
    }
    __syncthreads();

    // ---- phase 1: layer-1 GEMM -> spike mask in LDS ----
    bf16x8 af[NKT];
    #pragma unroll
    for (int kt = 0; kt < NKT; ++kt)
        af[kt] = *(const bf16x8*)&a_lds[m * 16 + l16][kt * 32 + quad * 8];

    {
        const __bf16* bp = B_sw + (size_t)lane * 8;
        float b1v[13];
        #pragma unroll
        for (int i = 0; i < 13; ++i) {
            int nt = 2 * i + h;
            b1v[i] = (nt < NT1) ? b1[nt * 16 + l16] : 0.f;
        }
        bf16x8 cur[NKT], nxt[NKT];
        {
            const __bf16* t0 = bp + (size_t)h * NKT * 512;
            #pragma unroll
            for (int kt = 0; kt < NKT; ++kt) cur[kt] = *(const bf16x8*)(t0 + (size_t)kt * 512);
        }
        #pragma unroll
        for (int i = 0; i < 13; ++i) {
            const int nt = 2 * i + h;
            if (nt < NT1) {
                const int nn = nt + 2;
                if (nn < NT1) {
                    const __bf16* tn = bp + (size_t)nn * NKT * 512;
                    #pragma unroll
                    for (int kt = 0; kt < NKT; ++kt) nxt[kt] = *(const bf16x8*)(tn + (size_t)kt * 512);
                }
                f32x4 acc = (f32x4){0.f, 0.f, 0.f, 0.f};
                #pragma unroll
                for (int kt = 0; kt < NKT; ++kt)
                    acc = __builtin_amdgcn_mfma_f32_16x16x32_bf16(af[kt], cur[kt], acc, 0, 0, 0);
                #pragma unroll
                for (int reg = 0; reg < 4; ++reg) {
                    // 0.99: superset of {x1_ref >= 1}; bf16 GEMM |err| << 0.01 at this K/scale
                    unsigned long long bal = __ballot(acc[reg] + b1v[i] >= 0.99f);
                    if (l16 == 0)
                        s_mask[m * 16 + quad * 4 + reg][nt] = (unsigned short)(bal >> (quad * 16));
                }
                #pragma unroll
                for (int kt = 0; kt < NKT; ++kt) cur[kt] = nxt[kt];
            }
        }
    }
    __syncthreads();

    // ---- phase 2: bound GEMM. bound[j] = b2[j] + sum_{i in mask} bf16(W2+[i][j]) ----
    {
        unsigned long long mw[7];
        const unsigned long long* mrow = (const unsigned long long*)&s_mask[m * 16 + l16][0];
        #pragma unroll
        for (int i = 0; i < 7; ++i) mw[i] = mrow[i];
        #pragma unroll
        for (int kt = 0; kt < NKT; ++kt) {
            const int bit0 = ((kt & 1) << 5) | (quad << 3);
            unsigned by = (unsigned)(mw[kt >> 1] >> bit0) & 0xFFu;
            #pragma unroll
            for (int e = 0; e < 8; ++e)
                af[kt][e] = ((by >> e) & 1u) ? (__bf16)1.0f : (__bf16)0.0f;
        }

        float b2v[10];
        #pragma unroll
        for (int i = 0; i < 10; ++i) {
            int nt = 2 * i + h;
            int j = nt * 16 + l16;
            b2v[i] = (nt < NT2 && j < H2) ? b2[j] : 0.f;
        }

        const __bf16* bp = B2_sw + (size_t)lane * 8;
        bool okr[4] = {true, true, true, true};
        bf16x8 cur[NKT], nxt[NKT];
        {
            const __bf16* t0 = bp + (size_t)h * NKT * 512;
            #pragma unroll
            for (int kt = 0; kt < NKT; ++kt) cur[kt] = *(const bf16x8*)(t0 + (size_t)kt * 512);
        }
        #pragma unroll
        for (int i = 0; i < 10; ++i) {
            const int nt = 2 * i + h;
            if (nt < NT2) {
                const int nn = nt + 2;
                if (nn < NT2) {
                    const __bf16* tn = bp + (size_t)nn * NKT * 512;
                    #pragma unroll
                    for (int kt = 0; kt < NKT; ++kt) nxt[kt] = *(const bf16x8*)(tn + (size_t)kt * 512);
                }
                f32x4 acc = (f32x4){0.f, 0.f, 0.f, 0.f};
                #pragma unroll
                for (int kt = 0; kt < NKT; ++kt)
                    acc = __builtin_amdgcn_mfma_f32_16x16x32_bf16(af[kt], cur[kt], acc, 0, 0, 0);
                #pragma unroll
                for (int reg = 0; reg < 4; ++reg)
                    okr[reg] = okr[reg] && (acc[reg] + b2v[i] < 0.92f);
                #pragma unroll
                for (int kt = 0; kt < NKT; ++kt) cur[kt] = nxt[kt];
            }
        }

        unsigned rowok_w = 0;
        #pragma unroll
        for (int reg = 0; reg < 4; ++reg) {
            unsigned long long bal = __ballot(okr[reg]);
            #pragma unroll
            for (int q = 0; q < 4; ++q)
                if (((bal >> (q * 16)) & 0xFFFFULL) == 0xFFFFULL)
                    rowok_w |= 1u << (q * 4 + reg);
        }
        if (lane == 0) s_ok[w] = rowok_w;
    }
    __syncthreads();
    const unsigned rowok = s_ok[m * 2] & s_ok[m * 2 + 1];
    if (h) return;   // odd waves done; wave (m,0) handles output/tier3 for mtile m
    const int rowbase = base + m * 16;

    // closed-form output if s2==0: v3 charges toward b3 (row-independent)
    const float b3v = (lane < ADIM) ? b3[lane] : 0.f;
    float gv;
    {
        float v3 = 0.f, vm = -3.0e38f;
        #pragma unroll
        for (int t = 0; t < TSTEPS; ++t) { v3 += (b3v - v3) * 0.5f; vm = fmaxf(vm, v3); }
        gv = 0.05f * tanhf(vm);
    }

    // write out for OK rows: 16 rows x 17 = 272 elems, coalesced over gi
    #pragma unroll
    for (int it = 0; it < 5; ++it) {
        int gi = it * 64 + lane;
        int r = gi / 17, d = gi - r * 17;
        float g = __shfl(gv, d);           // hoisted out of divergence
        if (r < 16 && ((rowok >> r) & 1u)) {
            size_t o = (size_t)(rowbase + r) * ADIM + d;
            out[o] = fminf(fmaxf(g + action[o], -1.f), 1.f);
        }
    }

    // tier3 (soundness net, never taken in practice): full f32 sim per failed row
    unsigned bad = (~rowok) & 0xFFFFu;
    if (bad == 0u) return;  // wave-uniform
    while (bad) {
        int rr = __builtin_ctz(bad); bad &= bad - 1;
        int row = rowbase + rr;
        float x1v[7];
        #pragma unroll
        for (int s = 0; s < 7; ++s) { int col = lane + 64 * s; x1v[s] = (col < H1) ? b1[col] : 0.f; }
        for (int k = 0; k < DIN; ++k) {
            float ik = (k < SDIM) ? state[(size_t)row * SDIM + k] : action[(size_t)row * ADIM + k - SDIM];
            #pragma unroll
            for (int s = 0; s < 7; ++s) {
                int col = lane + 64 * s;
                if (col < H1) x1v[s] += ik * W1[(size_t)k * H1 + col];
            }
        }
        float b2f[5];
        #pragma unroll
        for (int c = 0; c < 5; ++c) { int j = lane + 64 * c; b2f[c] = (j < H2) ? b2[j] : 0.f; }
        float v1[7], v2[5], v3 = 0.f, vmax = -3.0e38f;
        #pragma unroll
        for (int s = 0; s < 7; ++s) v1[s] = 0.f;
        #pragma unroll
        for (int c = 0; c < 5; ++c) v2[c] = 0.f;
        for (int t = 0; t < TSTEPS; ++t) {
            float x2[5];
            #pragma unroll
            for (int c = 0; c < 5; ++c) x2[c] = b2f[c];
            #pragma unroll
            for (int s = 0; s < 7; ++s) {
                float v = v1[s] + (x1v[s] - v1[s]) * 0.5f;
                bool sp = v >= 1.0f;
                v1[s] = sp ? 0.f : v;
                unsigned long long mm = __ballot(sp);
                while (mm) {
                    int j = __builtin_ctzll(mm); mm &= mm - 1;
                    const float* wr = W2 + (size_t)(s * 64 + j) * H2;
                    #pragma unroll
                    for (int c = 0; c < 5; ++c) {
                        int col = lane + 64 * c;
                        if (col < H2) x2[c] += wr[col];
                    }
                }
            }
            float x3 = b3v;
            #pragma unroll
            for (int c = 0; c < 5; ++c) {
                float v = v2[c] + (x2[c] - v2[c]) * 0.5f;
                int col = lane + 64 * c;
                bool sp = (col < H2) && (v >= 1.0f);
                v2[c] = sp ? 0.f : v;
                unsigned long long mm = __ballot(sp);
                while (mm) {
                    int j = __builtin_ctzll(mm); mm &= mm - 1;
                    if (lane < ADIM) x3 += W3[(size_t)(c * 64 + j) * ADIM + lane];
                }
            }
            v3 += (x3 - v3) * 0.5f;
            vmax = fmaxf(vmax, v3);
        }
        if (lane < ADIM)
            out[(size_t)row * ADIM + lane] =
                fminf(fmaxf(0.05f * tanhf(vmax) + action[(size_t)row * ADIM + lane], -1.f), 1.f);
    }
}

extern "C" void kernel_launch(void* const* d_in, const int* in_sizes, int n_in,
                              void* d_out, int out_size, void* d_ws, size_t ws_size,
                              hipStream_t stream) {
    const float* state  = (const float*)d_in[0];
    const float* action = (const float*)d_in[1];
    const float* W1     = (const float*)d_in[2];
    const float* b1     = (const float*)d_in[3];
    const float* W2     = (const float*)d_in[4];
    const float* b2     = (const float*)d_in[5];
    const float* W3     = (const float*)d_in[6];
    const float* b3     = (const float*)d_in[7];
    float* out = (float*)d_out;

    const int B = in_sizes[0] / SDIM;  // 8192

    char* p = (char*)d_ws;
    __bf16* B_sw = (__bf16*)p;                 p += (size_t)H1 * KP * 2;
    __bf16* B2_sw = (__bf16*)p;                p += (size_t)NT2 * NKT * 64 * 8 * 2;

    const int nw1 = (52 * H1 + 255) / 256;     // 82
    const int nw2 = (52 * 304 + 255) / 256;    // 62
    prep_w<<<nw1 + nw2, 256, 0, stream>>>(W1, W2, B_sw, B2_sw, nw1);
    mask_bound<<<B / 64, 512, 0, stream>>>(B_sw, B2_sw, state, action,
                                           W1, b1, W2, b2, W3, b3, out);
}

// Round 6
// 92.565 us; speedup vs baseline: 1.1075x; 1.1075x over previous
//
#include <hip/hip_runtime.h>
#include <math.h>

#define SDIM 376
#define ADIM 17
#define DIN  393
#define H1   400
#define H2   300
#define TSTEPS 32
#define KP 416   // 13*32 (padded DIN / padded H1 as K-dims)
#define NKT 13   // K tiles of 32
#define NT1 25   // n-tiles for H1 (400 cols, exact)
#define NT2 19   // n-tiles for H2 (304 padded cols)
#define LDA 424  // a_lds row stride in bf16 (pad 416+8: breaks 16-row bank aliasing)

typedef __bf16 bf16x8 __attribute__((ext_vector_type(8)));
typedef float  f32x4  __attribute__((ext_vector_type(4)));

// R5: revert R4's 64-row/128-block shape (half the CUs idle -> +5us regression;
// weights are L2-resident so "traffic" was the wrong lever). Back to 32 rows/block,
// grid 256 (1 block/CU), but now 512 thr = 8 waves: 2 mtiles x 4-way n-parity
// (m = w>>2, h = w&3) -> 2 waves/SIMD. R3 ran 1 wave/SIMD, latency-bound
// (~300cy L2 return vs 63cy MFMA chain per tile); the second wave/SIMD hides it.
// Per-wave inner code / chain order / thresholds bit-identical to R3.
// prep_w keeps R4's coalesced remap (8 coalesced reads + one 16B store per thread).

// ---------- K0: weights only. W1 -> B_sw | W2+ -> B2_sw ----------
__global__ __launch_bounds__(256) void prep_w(
    const float* __restrict__ W1, const float* __restrict__ W2,
    __bf16* __restrict__ B_sw, __bf16* __restrict__ B2_sw, int nw1) {
    const int bid = blockIdx.x, tid = threadIdx.x;
    if (bid < nw1) {
        // W1: thread handles k0..k0+7 (one e-run) for col n; per e, wave reads 256B
        // contiguous of W1; write is one contiguous bf16x8.
        int idx = bid * 256 + tid;
        if (idx >= 52 * H1) return;
        int kc = idx / H1, n = idx - kc * H1;
        int k0 = kc * 8;
        bf16x8 o;
        #pragma unroll
        for (int e = 0; e < 8; ++e) {
            int k = k0 + e;
            o[e] = (__bf16)((k < DIN) ? W1[(size_t)k * H1 + n] : 0.f);
        }
        int kt = k0 >> 5, qd = (k0 >> 3) & 3;
        *(bf16x8*)&B_sw[(((size_t)(n >> 4) * NKT + kt) * 64 + (qd << 4) + (n & 15)) * 8] = o;
    } else {
        // W2+ = max(W2,0): same mapping, n in [0,304) (pad cols write 0)
        int idx = (bid - nw1) * 256 + tid;
        if (idx >= 52 * 304) return;
        int kc = idx / 304, n = idx - kc * 304;
        int k0 = kc * 8;
        bf16x8 o;
        #pragma unroll
        for (int e = 0; e < 8; ++e) {
            int k = k0 + e;
            o[e] = (__bf16)((k < H1 && n < H2) ? fmaxf(W2[(size_t)k * H2 + n], 0.f) : 0.f);
        }
        int kt = k0 >> 5, qd = (k0 >> 3) & 3;
        *(bf16x8*)&B2_sw[(((size_t)(n >> 4) * NKT + kt) * 64 + (qd << 4) + (n & 15)) * 8] = o;
    }
}

// ---------- K1 (fused): pack -> layer-1 mask -> bound GEMM -> epilogue ----------
// 256 blocks x 512 thr (8 waves). Wave w: mtile m = w>>2 (16 rows), parity h = w&3
// (ntiles {h, h+4, ...}). Thresholds: mask 0.99 (superset of x1>=1), bound 0.92
// (bf16 undercount <= ~0.04; 0.92+0.04 < 0.999 => sound).
__global__ __launch_bounds__(512, 2) void mask_bound(
    const __bf16* __restrict__ B_sw, const __bf16* __restrict__ B2_sw,
    const float* __restrict__ state, const float* __restrict__ action,
    const float* __restrict__ W1, const float* __restrict__ b1,
    const float* __restrict__ W2, const float* __restrict__ b2,
    const float* __restrict__ W3, const float* __restrict__ b3,
    float* __restrict__ out) {
    const int tid = threadIdx.x;
    const int lane = tid & 63, w = tid >> 6;
    const int l16 = lane & 15, quad = lane >> 4;
    const int m = w >> 2, h = w & 3;
    const int base = blockIdx.x * 32;

    __shared__ __align__(16) __bf16 a_lds[32][LDA];            // 27136 B
    __shared__ __align__(16) unsigned short s_mask[32][32];    // 2048 B
    __shared__ unsigned s_ok[8];

    // zero mask chunks 25..31 (pad chunks must read as no-spike)
    if (tid < 224) { int rr = tid / 7, c7 = tid - rr * 7; s_mask[rr][25 + c7] = 0; }

    // ---- pack rows [base, base+32) -> a_lds (bf16 concat(state,action,0)) ----
    #pragma unroll
    for (int it = 0; it < 4; ++it) {
        int u = it * 512 + tid;
        if (u < 32 * 52) {
            int r = u / 52, cc = u - r * 52, g0 = cc * 8;
            const int grow = base + r;
            float v[8];
            if (g0 + 7 < SDIM) {
                float4 a = *(const float4*)&state[(size_t)grow * SDIM + g0];
                float4 b = *(const float4*)&state[(size_t)grow * SDIM + g0 + 4];
                v[0]=a.x; v[1]=a.y; v[2]=a.z; v[3]=a.w; v[4]=b.x; v[5]=b.y; v[6]=b.z; v[7]=b.w;
            } else {
                #pragma unroll
                for (int e = 0; e < 8; ++e) {
                    int k = g0 + e;
                    v[e] = (k < SDIM) ? state[(size_t)grow * SDIM + k]
                         : (k < DIN)  ? action[(size_t)grow * ADIM + k - SDIM] : 0.f;
                }
            }
            bf16x8 o;
            #pragma unroll
            for (int e = 0; e < 8; ++e) o[e] = (__bf16)v[e];
            *(bf16x8*)&a_lds[r][g0] = o;
        }
    }
    __syncthreads();

    // ---- phase 1: layer-1 GEMM -> spike mask in LDS ----
    bf16x8 af[NKT];
    #pragma unroll
    for (int kt = 0; kt < NKT; ++kt)
        af[kt] = *(const bf16x8*)&a_lds[m * 16 + l16][kt * 32 + quad * 8];

    {
        const __bf16* bp = B_sw + (size_t)lane * 8;
        float b1v[7];
        #pragma unroll
        for (int i = 0; i < 7; ++i) {
            int nt = 4 * i + h;
            b1v[i] = (nt < NT1) ? b1[nt * 16 + l16] : 0.f;
        }
        bf16x8 cur[NKT], nxt[NKT];
        {
            const __bf16* t0 = bp + (size_t)h * NKT * 512;
            #pragma unroll
            for (int kt = 0; kt < NKT; ++kt) cur[kt] = *(const bf16x8*)(t0 + (size_t)kt * 512);
        }
        #pragma unroll
        for (int i = 0; i < 7; ++i) {
            const int nt = 4 * i + h;
            if (nt < NT1) {
                const int nn = nt + 4;
                if (nn < NT1) {
                    const __bf16* tn = bp + (size_t)nn * NKT * 512;
                    #pragma unroll
                    for (int kt = 0; kt < NKT; ++kt) nxt[kt] = *(const bf16x8*)(tn + (size_t)kt * 512);
                }
                f32x4 acc = (f32x4){0.f, 0.f, 0.f, 0.f};
                #pragma unroll
                for (int kt = 0; kt < NKT; ++kt)
                    acc = __builtin_amdgcn_mfma_f32_16x16x32_bf16(af[kt], cur[kt], acc, 0, 0, 0);
                #pragma unroll
                for (int reg = 0; reg < 4; ++reg) {
                    // 0.99: superset of {x1_ref >= 1}; bf16 GEMM |err| << 0.01 at this K/scale
                    unsigned long long bal = __ballot(acc[reg] + b1v[i] >= 0.99f);
                    if (l16 == 0)
                        s_mask[m * 16 + quad * 4 + reg][nt] = (unsigned short)(bal >> (quad * 16));
                }
                #pragma unroll
                for (int kt = 0; kt < NKT; ++kt) cur[kt] = nxt[kt];
            }
        }
    }
    __syncthreads();

    // ---- phase 2: bound GEMM. bound[j] = b2[j] + sum_{i in mask} bf16(W2+[i][j]) ----
    {
        unsigned long long mw[7];
        const unsigned long long* mrow = (const unsigned long long*)&s_mask[m * 16 + l16][0];
        #pragma unroll
        for (int i = 0; i < 7; ++i) mw[i] = mrow[i];
        #pragma unroll
        for (int kt = 0; kt < NKT; ++kt) {
            const int bit0 = ((kt & 1) << 5) | (quad << 3);
            unsigned by = (unsigned)(mw[kt >> 1] >> bit0) & 0xFFu;
            #pragma unroll
            for (int e = 0; e < 8; ++e)
                af[kt][e] = ((by >> e) & 1u) ? (__bf16)1.0f : (__bf16)0.0f;
        }

        float b2v[5];
        #pragma unroll
        for (int i = 0; i < 5; ++i) {
            int nt = 4 * i + h;
            int j = nt * 16 + l16;
            b2v[i] = (nt < NT2 && j < H2) ? b2[j] : 0.f;
        }

        const __bf16* bp = B2_sw + (size_t)lane * 8;
        bool okr[4] = {true, true, true, true};
        bf16x8 cur[NKT], nxt[NKT];
        {
            const __bf16* t0 = bp + (size_t)h * NKT * 512;
            #pragma unroll
            for (int kt = 0; kt < NKT; ++kt) cur[kt] = *(const bf16x8*)(t0 + (size_t)kt * 512);
        }
        #pragma unroll
        for (int i = 0; i < 5; ++i) {
            const int nt = 4 * i + h;
            if (nt < NT2) {
                const int nn = nt + 4;
                if (nn < NT2) {
                    const __bf16* tn = bp + (size_t)nn * NKT * 512;
                    #pragma unroll
                    for (int kt = 0; kt < NKT; ++kt) nxt[kt] = *(const bf16x8*)(tn + (size_t)kt * 512);
                }
                f32x4 acc = (f32x4){0.f, 0.f, 0.f, 0.f};
                #pragma unroll
                for (int kt = 0; kt < NKT; ++kt)
                    acc = __builtin_amdgcn_mfma_f32_16x16x32_bf16(af[kt], cur[kt], acc, 0, 0, 0);
                #pragma unroll
                for (int reg = 0; reg < 4; ++reg)
                    okr[reg] = okr[reg] && (acc[reg] + b2v[i] < 0.92f);
                #pragma unroll
                for (int kt = 0; kt < NKT; ++kt) cur[kt] = nxt[kt];
            }
        }

        unsigned rowok_w = 0;
        #pragma unroll
        for (int reg = 0; reg < 4; ++reg) {
            unsigned long long bal = __ballot(okr[reg]);
            #pragma unroll
            for (int q = 0; q < 4; ++q)
                if (((bal >> (q * 16)) & 0xFFFFULL) == 0xFFFFULL)
                    rowok_w |= 1u << (q * 4 + reg);
        }
        if (lane == 0) s_ok[w] = rowok_w;
    }
    __syncthreads();
    const unsigned rowok = s_ok[m * 4] & s_ok[m * 4 + 1] & s_ok[m * 4 + 2] & s_ok[m * 4 + 3];
    if (h) return;   // waves h!=0 done; wave (m,0) handles output/tier3 for mtile m
    const int rowbase = base + m * 16;

    // closed-form output if s2==0: v3 charges toward b3 (row-independent)
    const float b3v = (lane < ADIM) ? b3[lane] : 0.f;
    float gv;
    {
        float v3 = 0.f, vm = -3.0e38f;
        #pragma unroll
        for (int t = 0; t < TSTEPS; ++t) { v3 += (b3v - v3) * 0.5f; vm = fmaxf(vm, v3); }
        gv = 0.05f * tanhf(vm);
    }

    // write out for OK rows: 16 rows x 17 = 272 elems, coalesced over gi
    #pragma unroll
    for (int it = 0; it < 5; ++it) {
        int gi = it * 64 + lane;
        int r = gi / 17, d = gi - r * 17;
        float g = __shfl(gv, d);           // hoisted out of divergence
        if (r < 16 && ((rowok >> r) & 1u)) {
            size_t o = (size_t)(rowbase + r) * ADIM + d;
            out[o] = fminf(fmaxf(g + action[o], -1.f), 1.f);
        }
    }

    // tier3 (soundness net, never taken in practice): full f32 sim per failed row
    unsigned bad = (~rowok) & 0xFFFFu;
    if (bad == 0u) return;  // wave-uniform
    while (bad) {
        int rr = __builtin_ctz(bad); bad &= bad - 1;
        int row = rowbase + rr;
        float x1v[7];
        #pragma unroll
        for (int s = 0; s < 7; ++s) { int col = lane + 64 * s; x1v[s] = (col < H1) ? b1[col] : 0.f; }
        for (int k = 0; k < DIN; ++k) {
            float ik = (k < SDIM) ? state[(size_t)row * SDIM + k] : action[(size_t)row * ADIM + k - SDIM];
            #pragma unroll
            for (int s = 0; s < 7; ++s) {
                int col = lane + 64 * s;
                if (col < H1) x1v[s] += ik * W1[(size_t)k * H1 + col];
            }
        }
        float b2f[5];
        #pragma unroll
        for (int c = 0; c < 5; ++c) { int j = lane + 64 * c; b2f[c] = (j < H2) ? b2[j] : 0.f; }
        float v1[7], v2[5], v3 = 0.f, vmax = -3.0e38f;
        #pragma unroll
        for (int s = 0; s < 7; ++s) v1[s] = 0.f;
        #pragma unroll
        for (int c = 0; c < 5; ++c) v2[c] = 0.f;
        for (int t = 0; t < TSTEPS; ++t) {
            float x2[5];
            #pragma unroll
            for (int c = 0; c < 5; ++c) x2[c] = b2f[c];
            #pragma unroll
            for (int s = 0; s < 7; ++s) {
                float v = v1[s] + (x1v[s] - v1[s]) * 0.5f;
                bool sp = v >= 1.0f;
                v1[s] = sp ? 0.f : v;
                unsigned long long mm = __ballot(sp);
                while (mm) {
                    int j = __builtin_ctzll(mm); mm &= mm - 1;
                    const float* wr = W2 + (size_t)(s * 64 + j) * H2;
                    #pragma unroll
                    for (int c = 0; c < 5; ++c) {
                        int col = lane + 64 * c;
                        if (col < H2) x2[c] += wr[col];
                    }
                }
            }
            float x3 = b3v;
            #pragma unroll
            for (int c = 0; c < 5; ++c) {
                float v = v2[c] + (x2[c] - v2[c]) * 0.5f;
                int col = lane + 64 * c;
                bool sp = (col < H2) && (v >= 1.0f);
                v2[c] = sp ? 0.f : v;
                unsigned long long mm = __ballot(sp);
                while (mm) {
                    int j = __builtin_ctzll(mm); mm &= mm - 1;
                    if (lane < ADIM) x3 += W3[(size_t)(c * 64 + j) * ADIM + lane];
                }
            }
            v3 += (x3 - v3) * 0.5f;
            vmax = fmaxf(vmax, v3);
        }
        if (lane < ADIM)
            out[(size_t)row * ADIM + lane] =
                fminf(fmaxf(0.05f * tanhf(vmax) + action[(size_t)row * ADIM + lane], -1.f), 1.f);
    }
}

extern "C" void kernel_launch(void* const* d_in, const int* in_sizes, int n_in,
                              void* d_out, int out_size, void* d_ws, size_t ws_size,
                              hipStream_t stream) {
    const float* state  = (const float*)d_in[0];
    const float* action = (const float*)d_in[1];
    const float* W1     = (const float*)d_in[2];
    const float* b1     = (const float*)d_in[3];
    const float* W2     = (const float*)d_in[4];
    const float* b2     = (const float*)d_in[5];
    const float* W3     = (const float*)d_in[6];
    const float* b3     = (const float*)d_in[7];
    float* out = (float*)d_out;

    const int B = in_sizes[0] / SDIM;  // 8192

    char* p = (char*)d_ws;
    __bf16* B_sw = (__bf16*)p;                 p += (size_t)H1 * KP * 2;
    __bf16* B2_sw = (__bf16*)p;                p += (size_t)NT2 * NKT * 64 * 8 * 2;

    const int nw1 = (52 * H1 + 255) / 256;     // 82
    const int nw2 = (52 * 304 + 255) / 256;    // 62
    prep_w<<<nw1 + nw2, 256, 0, stream>>>(W1, W2, B_sw, B2_sw, nw1);
    mask_bound<<<B / 32, 512, 0, stream>>>(B_sw, B2_sw, state, action,
                                           W1, b1, W2, b2, W3, b3, out);
}